// Round 1
// baseline (335.911 us; speedup 1.0000x reference)
//
#include <hip/hip_runtime.h>

#define CAP  256    // max candidates per image (expected ~66, ~23 sigma margin)
#define KDET 300
#define NW   4      // ceil(CAP/64) suppression-mask words
#define SCAN_BDIM 256
#define NMS_BDIM  256

// ---------------------------------------------------------------------------
// Kernel 1: full-GPU scan + decode.
// One thread per (image, scale, anchor, pixel): 64*3*3549 = 681,408 threads.
// Scale range boundaries are multiples of 64 -> no intra-wave scale divergence.
// Passing threads (~0.6%) decode (incl. 80-class argmax) and append an 8-float
// record to a per-image global candidate list in the workspace.
// ---------------------------------------------------------------------------
template<int HW, int W, int BASE>
__device__ __forceinline__ void scan_one(int rem, float stride,
        const float* __restrict__ op, const float* __restrict__ an,
        float thr, int* __restrict__ counters, float* __restrict__ cand) {
    int n   = rem / (3 * HW);           // compile-time divisor -> magic mul
    int q   = rem - n * (3 * HW);
    int a   = q / HW;
    int pix = q - a * HW;

    const float* p = op + ((size_t)(n * 255 + a * 85)) * HW + pix;
    float conf = p[0];                  // coalesced: consecutive t -> consecutive pix
    if (!(conf > thr)) return;

    float o1 = p[(size_t)1 * HW];
    float o2 = p[(size_t)2 * HW];
    float o3 = p[(size_t)3 * HW];
    float o4 = p[(size_t)4 * HW];
    int gx = pix % W, gy = pix / W;
    float ox = ((float)gx + o1) * stride;
    float oy = ((float)gy + o2) * stride;
    float bw = expf(o3) * an[2 * a + 0];
    float bh = expf(o4) * an[2 * a + 1];

    float best = p[(size_t)5 * HW];     // argmax, strict > = first occurrence
    int cls = 0;
    #pragma unroll 4
    for (int c = 1; c < 80; ++c) {
        float v = p[(size_t)(5 + c) * HW];
        if (v > best) { best = v; cls = c; }
    }

    int slot = atomicAdd(counters + n, 1);   // device-scope, cross-block safe
    if (slot < CAP) {
        float4* w4 = (float4*)(cand + ((size_t)n * CAP + slot) * 8);
        w4[0] = make_float4(conf, ox, oy, bw);
        w4[1] = make_float4(bh, (float)cls, (float)(BASE + pix * 3 + a), 0.f);
    }
}

__global__ __launch_bounds__(SCAN_BDIM) void yolo_scan_kernel(
        const float* __restrict__ o13, const float* __restrict__ o26,
        const float* __restrict__ o52,
        const float* __restrict__ a13, const float* __restrict__ a26,
        const float* __restrict__ a52,
        const float* __restrict__ thresh_p, int N,
        int* __restrict__ counters, float* __restrict__ cand) {
    int t = blockIdx.x * SCAN_BDIM + threadIdx.x;
    float thr = *thresh_p;
    int R0 = N * 507;            // 3*169  per image
    int R1 = N * 2028;           // 3*676  per image
    int R2 = N * 8112;           // 3*2704 per image
    if (t < R0) {
        scan_one<169, 13, 0>(t, 32.f, o13, a13, thr, counters, cand);
    } else if (t < R0 + R1) {
        scan_one<676, 26, 507>(t - R0, 16.f, o26, a26, thr, counters, cand);
    } else if (t < R0 + R1 + R2) {
        scan_one<2704, 52, 2535>(t - R0 - R1, 8.f, o52, a52, thr, counters, cand);
    }
}

// ---------------------------------------------------------------------------
// Kernel 2: per-image rank-sort + NMS + write. One block per image; all work
// is O(cnt^2) with cnt ~ 66, so a 256-thread block finishes in a few us.
// ---------------------------------------------------------------------------
__global__ __launch_bounds__(NMS_BDIM) void yolo_nms_kernel(
        const int* __restrict__ counters, const float* __restrict__ cand,
        float* __restrict__ out) {
    int n = blockIdx.x, tid = threadIdx.x;

    __shared__ float s_conf[CAP], s_cx[CAP], s_cy[CAP], s_w[CAP], s_h[CAP],
                     s_cls[CAP], s_idx[CAP];
    __shared__ float r_conf[CAP], r_cx[CAP], r_cy[CAP], r_w[CAP], r_h[CAP], r_cls[CAP];
    __shared__ float s_x1[CAP], s_y1[CAP], s_x2[CAP], s_y2[CAP];
    __shared__ unsigned long long sup[CAP][NW];
    __shared__ unsigned long long keepmask[NW];

    int cnt = counters[n];
    cnt = cnt < CAP ? cnt : CAP;         // cnt <= 256 < KDET

    // load candidates (two float4 per record)
    for (int i = tid; i < cnt; i += NMS_BDIM) {
        const float4* c4 = (const float4*)(cand + ((size_t)n * CAP + i) * 8);
        float4 lo = c4[0], hi = c4[1];
        s_conf[i] = lo.x; s_cx[i] = lo.y; s_cy[i] = lo.z; s_w[i] = lo.w;
        s_h[i]   = hi.x; s_cls[i] = hi.y; s_idx[i] = hi.z;
    }
    __syncthreads();

    // rank-sort (descending conf, ties -> lower concat idx)  == top_k semantics
    for (int i = tid; i < cnt; i += NMS_BDIM) {
        float ci = s_conf[i], ii = s_idx[i];
        int rank = 0;
        for (int j = 0; j < cnt; ++j) {
            float cj = s_conf[j];
            rank += (cj > ci) || (cj == ci && s_idx[j] < ii);
        }
        float cx = s_cx[i], cy = s_cy[i], w = s_w[i], h = s_h[i];
        r_conf[rank] = ci; r_cx[rank] = cx; r_cy[rank] = cy;
        r_w[rank] = w;     r_h[rank] = h;   r_cls[rank] = s_cls[i];
        s_x1[rank] = cx - 0.5f * w;
        s_y1[rank] = cy - 0.5f * h;
        s_x2[rank] = cx + 0.5f * w;
        s_y2[rank] = cy + 0.5f * h;
    }
    __syncthreads();

    // suppression bitmask (iou > 0.3 && same class)
    int nwords = (cnt + 63) >> 6;
    for (int t = tid; t < cnt * NW; t += NMS_BDIM) {
        int i  = t >> 2;
        int wi = t & 3;
        if (wi >= nwords) continue;
        float xi1 = s_x1[i], yi1 = s_y1[i], xi2 = s_x2[i], yi2 = s_y2[i];
        float cli = r_cls[i];
        float area_i = (xi2 - xi1) * (yi2 - yi1);
        unsigned long long m = 0;
        int jbase = wi << 6;
        for (int b = 0; b < 64; ++b) {
            int j = jbase + b;
            if (j >= cnt) break;
            if (j == i) continue;
            float xl = fmaxf(xi1, s_x1[j]);
            float yt = fmaxf(yi1, s_y1[j]);
            float xr = fminf(xi2, s_x2[j]);
            float yb = fminf(yi2, s_y2[j]);
            float inter  = fmaxf(xr - xl, 0.f) * fmaxf(yb - yt, 0.f);
            float area_j = (s_x2[j] - s_x1[j]) * (s_y2[j] - s_y1[j]);
            float iou    = inter / fmaxf(area_i + area_j - inter, 1e-9f);
            if (iou > 0.3f && cli == r_cls[j]) m |= (1ull << b);
        }
        sup[i][wi] = m;
    }
    __syncthreads();

    // greedy scan (sequential, thread 0; cnt ~ 66 iterations)
    if (tid == 0) {
        unsigned long long km[NW];
        for (int w = 0; w < NW; ++w) km[w] = 0ull;
        for (int i = 0; i < cnt; ++i) {
            unsigned long long sbits = 0;
            for (int w = 0; w < nwords; ++w) sbits |= sup[i][w] & km[w];
            if (sbits == 0) km[i >> 6] |= (1ull << (i & 63));
        }
        for (int w = 0; w < NW; ++w) keepmask[w] = km[w];
    }
    __syncthreads();

    // write (KDET,7), zeros for suppressed/invalid rows
    float* obase = out + (size_t)n * KDET * 7;
    float nf = (float)n;
    for (int t = tid; t < KDET * 7; t += NMS_BDIM) {
        int r = t / 7, c = t - r * 7;
        float v = 0.f;
        if (r < cnt && ((keepmask[r >> 6] >> (r & 63)) & 1ull)) {
            switch (c) {
                case 0: v = r_conf[r]; break;
                case 1: v = r_cx[r];   break;
                case 2: v = r_cy[r];   break;
                case 3: v = r_w[r];    break;
                case 4: v = r_h[r];    break;
                case 5: v = r_cls[r];  break;
                case 6: v = nf;        break;
            }
        }
        obase[t] = v;
    }
}

// ---------------------------------------------------------------------------
// Fallback: previous verified single-kernel version (used only if the
// workspace is too small for the two-kernel path).
// ---------------------------------------------------------------------------
#define BDIM 512
__global__ __launch_bounds__(BDIM) void yolo_fused_kernel(
        const float* __restrict__ o13, const float* __restrict__ o26,
        const float* __restrict__ o52,
        const float* __restrict__ a13, const float* __restrict__ a26,
        const float* __restrict__ a52,
        const float* __restrict__ thresh_p,
        float* __restrict__ out) {
    int n   = blockIdx.x;
    int tid = threadIdx.x;

    __shared__ int   l_cnt;
    __shared__ int   l_pack[CAP];
    __shared__ float l_conf[CAP];
    __shared__ float s_conf[CAP], s_cx[CAP], s_cy[CAP], s_w[CAP], s_h[CAP],
                     s_cls[CAP], s_idx[CAP];
    __shared__ float r_conf[CAP], r_cx[CAP], r_cy[CAP], r_w[CAP], r_h[CAP], r_cls[CAP];
    __shared__ float s_x1[CAP], s_y1[CAP], s_x2[CAP], s_y2[CAP];
    __shared__ unsigned long long sup[CAP][NW];
    __shared__ unsigned long long keepmask[NW];

    if (tid == 0) l_cnt = 0;
    __syncthreads();

    float thr = *thresh_p;

    for (int t = tid; t < 507; t += BDIM) {
        int a = t / 169, pix = t - a * 169;
        float conf = o13[((size_t)(n * 255 + a * 85)) * 169 + pix];
        if (conf > thr) {
            int slot = atomicAdd(&l_cnt, 1);
            if (slot < CAP) { l_pack[slot] = (0 << 16) | (a << 12) | pix; l_conf[slot] = conf; }
        }
    }
    for (int t = tid; t < 507; t += BDIM) {
        int a = t / 169, v = t - a * 169;
        const float4 c4 = *(const float4*)(o26 + ((size_t)(n * 255 + a * 85)) * 676 + v * 4);
        #pragma unroll
        for (int k = 0; k < 4; ++k) {
            float conf = (&c4.x)[k];
            if (conf > thr) {
                int slot = atomicAdd(&l_cnt, 1);
                if (slot < CAP) { l_pack[slot] = (1 << 16) | (a << 12) | (v * 4 + k); l_conf[slot] = conf; }
            }
        }
    }
    for (int t = tid; t < 2028; t += BDIM) {
        int a = t / 676, v = t - a * 676;
        const float4 c4 = *(const float4*)(o52 + ((size_t)(n * 255 + a * 85)) * 2704 + v * 4);
        #pragma unroll
        for (int k = 0; k < 4; ++k) {
            float conf = (&c4.x)[k];
            if (conf > thr) {
                int slot = atomicAdd(&l_cnt, 1);
                if (slot < CAP) { l_pack[slot] = (2 << 16) | (a << 12) | (v * 4 + k); l_conf[slot] = conf; }
            }
        }
    }
    __syncthreads();
    int cnt = l_cnt < CAP ? l_cnt : CAP;

    for (int i = tid; i < cnt; i += BDIM) {
        int pk  = l_pack[i];
        int s   = pk >> 16;
        int a   = (pk >> 12) & 0xF;
        int pix = pk & 0xFFF;
        const float* op = (s == 0) ? o13 : (s == 1) ? o26 : o52;
        const float* an = (s == 0) ? a13 : (s == 1) ? a26 : a52;
        int   HW     = (s == 0) ? 169 : (s == 1) ? 676 : 2704;
        int   W      = (s == 0) ? 13  : (s == 1) ? 26  : 52;
        float stride = (s == 0) ? 32.f : (s == 1) ? 16.f : 8.f;
        int   base   = (s == 0) ? 0   : (s == 1) ? 507 : 2535;

        const float* p = op + ((size_t)(n * 255 + a * 85)) * HW + pix;
        float o1 = p[(size_t)1 * HW];
        float o2 = p[(size_t)2 * HW];
        float o3 = p[(size_t)3 * HW];
        float o4 = p[(size_t)4 * HW];
        int gx = pix % W, gy = pix / W;
        float ox = ((float)gx + o1) * stride;
        float oy = ((float)gy + o2) * stride;
        float bw = expf(o3) * an[2 * a + 0];
        float bh = expf(o4) * an[2 * a + 1];

        float best = p[(size_t)5 * HW];
        int cls = 0;
        for (int c = 1; c < 80; ++c) {
            float v = p[(size_t)(5 + c) * HW];
            if (v > best) { best = v; cls = c; }
        }

        s_conf[i] = l_conf[i];
        s_cx[i] = ox; s_cy[i] = oy; s_w[i] = bw; s_h[i] = bh;
        s_cls[i] = (float)cls;
        s_idx[i] = (float)(base + pix * 3 + a);
    }
    __syncthreads();

    for (int i = tid; i < cnt; i += BDIM) {
        float ci = s_conf[i], ii = s_idx[i];
        int rank = 0;
        for (int j = 0; j < cnt; ++j) {
            float cj = s_conf[j];
            rank += (cj > ci) || (cj == ci && s_idx[j] < ii);
        }
        float cx = s_cx[i], cy = s_cy[i], w = s_w[i], h = s_h[i];
        r_conf[rank] = ci; r_cx[rank] = cx; r_cy[rank] = cy;
        r_w[rank] = w;     r_h[rank] = h;   r_cls[rank] = s_cls[i];
        s_x1[rank] = cx - 0.5f * w;
        s_y1[rank] = cy - 0.5f * h;
        s_x2[rank] = cx + 0.5f * w;
        s_y2[rank] = cy + 0.5f * h;
    }
    __syncthreads();

    int nwords = (cnt + 63) >> 6;
    int items  = cnt * nwords;
    for (int t = tid; t < items; t += BDIM) {
        int i  = t / nwords;
        int wi = t - i * nwords;
        float xi1 = s_x1[i], yi1 = s_y1[i], xi2 = s_x2[i], yi2 = s_y2[i];
        float cli = r_cls[i];
        float area_i = (xi2 - xi1) * (yi2 - yi1);
        unsigned long long m = 0;
        int jbase = wi << 6;
        for (int b = 0; b < 64; ++b) {
            int j = jbase + b;
            if (j >= cnt) break;
            if (j == i) continue;
            float xl = fmaxf(xi1, s_x1[j]);
            float yt = fmaxf(yi1, s_y1[j]);
            float xr = fminf(xi2, s_x2[j]);
            float yb = fminf(yi2, s_y2[j]);
            float inter  = fmaxf(xr - xl, 0.f) * fmaxf(yb - yt, 0.f);
            float area_j = (s_x2[j] - s_x1[j]) * (s_y2[j] - s_y1[j]);
            float iou    = inter / fmaxf(area_i + area_j - inter, 1e-9f);
            if (iou > 0.3f && cli == r_cls[j]) m |= (1ull << b);
        }
        sup[i][wi] = m;
    }
    __syncthreads();

    if (tid == 0) {
        unsigned long long km[NW];
        for (int w = 0; w < NW; ++w) km[w] = 0ull;
        for (int i = 0; i < cnt; ++i) {
            unsigned long long sbits = 0;
            for (int w = 0; w < nwords; ++w) sbits |= sup[i][w] & km[w];
            if (sbits == 0) km[i >> 6] |= (1ull << (i & 63));
        }
        for (int w = 0; w < NW; ++w) keepmask[w] = km[w];
    }
    __syncthreads();

    float* obase = out + (size_t)n * KDET * 7;
    float nf = (float)n;
    for (int t = tid; t < KDET * 7; t += BDIM) {
        int r = t / 7, c = t - r * 7;
        float v = 0.f;
        if (r < cnt && ((keepmask[r >> 6] >> (r & 63)) & 1ull)) {
            switch (c) {
                case 0: v = r_conf[r]; break;
                case 1: v = r_cx[r];   break;
                case 2: v = r_cy[r];   break;
                case 3: v = r_w[r];    break;
                case 4: v = r_h[r];    break;
                case 5: v = r_cls[r];  break;
                case 6: v = nf;        break;
            }
        }
        obase[t] = v;
    }
}

extern "C" void kernel_launch(void* const* d_in, const int* in_sizes, int n_in,
                              void* d_out, int out_size, void* d_ws, size_t ws_size,
                              hipStream_t stream) {
    const float* out13 = (const float*)d_in[0];
    const float* out26 = (const float*)d_in[1];
    const float* out52 = (const float*)d_in[2];
    const float* a13   = (const float*)d_in[3];
    const float* a26   = (const float*)d_in[4];
    const float* a52   = (const float*)d_in[5];
    const float* thr   = (const float*)d_in[6];
    float* out = (float*)d_out;

    int N = in_sizes[0] / (255 * 13 * 13);   // 64

    // workspace layout: [0,256): int counters[N]; [256, ...): float cand[N][CAP][8]
    size_t req = 256 + (size_t)N * CAP * 8 * sizeof(float);
    if (d_ws != nullptr && ws_size >= req) {
        int*   counters = (int*)d_ws;
        float* cand     = (float*)((char*)d_ws + 256);
        hipMemsetAsync(counters, 0, (size_t)N * sizeof(int), stream);
        int total  = N * 10647;              // N * 3 * (169 + 676 + 2704)
        int blocks = (total + SCAN_BDIM - 1) / SCAN_BDIM;
        yolo_scan_kernel<<<blocks, SCAN_BDIM, 0, stream>>>(
            out13, out26, out52, a13, a26, a52, thr, N, counters, cand);
        yolo_nms_kernel<<<N, NMS_BDIM, 0, stream>>>(counters, cand, out);
    } else {
        yolo_fused_kernel<<<N, BDIM, 0, stream>>>(out13, out26, out52,
                                                  a13, a26, a52, thr, out);
    }
}

// Round 2
// 320.187 us; speedup vs baseline: 1.0491x; 1.0491x over previous
//
#include <hip/hip_runtime.h>

#define CAP   240   // candidates/image staged in out-block scratch (expected 66±8)
#define KDET  300
#define OSTR  2100  // 300*7 floats per image in d_out
#define CNT_OFF 2096 // int counter at float offset 2096 of each image's block
#define NW    4     // ceil(CAP/64) suppression-mask words
#define SCAN_BDIM 256
#define NMS_BDIM  256

// ---------------------------------------------------------------------------
// Kernel 0: zero the 64 per-image candidate counters (scattered in d_out,
// one per image block, each in its own cacheline). One tiny block.
// ---------------------------------------------------------------------------
__global__ void yolo_zero_kernel(float* __restrict__ out, int N) {
    int n = threadIdx.x;
    if (n < N) ((int*)out)[(size_t)n * OSTR + CNT_OFF] = 0;
}

// ---------------------------------------------------------------------------
// Kernel 1: full-GPU scan + decode.
// One thread per (image, scale, anchor, pixel): 64*3*3549 = 681,408 threads.
// Passing threads (~0.6%) decode (incl. 80-class argmax) and append an
// 8-float record into their image's out-block scratch region [0, CAP*8).
// NO workspace bytes touched -> no workspace re-poison fill.
// ---------------------------------------------------------------------------
template<int HW, int W, int BASE>
__device__ __forceinline__ void scan_one(int rem, float stride,
        const float* __restrict__ op, const float* __restrict__ an,
        float thr, float* __restrict__ out) {
    int n   = rem / (3 * HW);           // compile-time divisor -> magic mul
    int q   = rem - n * (3 * HW);
    int a   = q / HW;
    int pix = q - a * HW;

    const float* p = op + ((size_t)(n * 255 + a * 85)) * HW + pix;
    float conf = p[0];                  // coalesced: consecutive t -> consecutive pix
    if (!(conf > thr)) return;

    float o1 = p[(size_t)1 * HW];
    float o2 = p[(size_t)2 * HW];
    float o3 = p[(size_t)3 * HW];
    float o4 = p[(size_t)4 * HW];
    int gx = pix % W, gy = pix / W;
    float ox = ((float)gx + o1) * stride;
    float oy = ((float)gy + o2) * stride;
    float bw = expf(o3) * an[2 * a + 0];
    float bh = expf(o4) * an[2 * a + 1];

    float best = p[(size_t)5 * HW];     // argmax, strict > = first occurrence
    int cls = 0;
    #pragma unroll 4
    for (int c = 1; c < 80; ++c) {
        float v = p[(size_t)(5 + c) * HW];
        if (v > best) { best = v; cls = c; }
    }

    int* cntp = (int*)out + (size_t)n * OSTR + CNT_OFF;
    int slot = atomicAdd(cntp, 1);      // device-scope, cross-block safe
    if (slot < CAP) {
        float4* w4 = (float4*)(out + (size_t)n * OSTR + slot * 8);
        w4[0] = make_float4(conf, ox, oy, bw);
        w4[1] = make_float4(bh, (float)cls, (float)(BASE + pix * 3 + a), 0.f);
    }
}

__global__ __launch_bounds__(SCAN_BDIM) void yolo_scan_kernel(
        const float* __restrict__ o13, const float* __restrict__ o26,
        const float* __restrict__ o52,
        const float* __restrict__ a13, const float* __restrict__ a26,
        const float* __restrict__ a52,
        const float* __restrict__ thresh_p, int N,
        float* __restrict__ out) {
    int t = blockIdx.x * SCAN_BDIM + threadIdx.x;
    float thr = *thresh_p;
    int R0 = N * 507;            // 3*169  per image
    int R1 = N * 2028;           // 3*676  per image
    int R2 = N * 8112;           // 3*2704 per image
    if (t < R0) {
        scan_one<169, 13, 0>(t, 32.f, o13, a13, thr, out);
    } else if (t < R0 + R1) {
        scan_one<676, 26, 507>(t - R0, 16.f, o26, a26, thr, out);
    } else if (t < R0 + R1 + R2) {
        scan_one<2704, 52, 2535>(t - R0 - R1, 8.f, o52, a52, thr, out);
    }
}

// ---------------------------------------------------------------------------
// Kernel 2: per-image rank-sort + NMS + write. One block per image.
// Reads image n's scratch (candidates + counter) from out-block n into LDS,
// then overwrites the whole block with the final (KDET,7) rows.
// Only block n touches block n -> no cross-block hazard.
// ---------------------------------------------------------------------------
__global__ __launch_bounds__(NMS_BDIM) void yolo_nms_kernel(
        float* __restrict__ out) {
    int n = blockIdx.x, tid = threadIdx.x;

    __shared__ float s_conf[CAP], s_cx[CAP], s_cy[CAP], s_w[CAP], s_h[CAP],
                     s_cls[CAP], s_idx[CAP];
    __shared__ float r_conf[CAP], r_cx[CAP], r_cy[CAP], r_w[CAP], r_h[CAP], r_cls[CAP];
    __shared__ float s_x1[CAP], s_y1[CAP], s_x2[CAP], s_y2[CAP];
    __shared__ unsigned long long sup[CAP][NW];
    __shared__ unsigned long long keepmask[NW];

    float* blk = out + (size_t)n * OSTR;
    int cnt = ((const int*)out)[(size_t)n * OSTR + CNT_OFF];
    cnt = cnt < CAP ? cnt : CAP;         // cnt <= 240 < KDET

    // load candidates (two float4 per record) from out-block scratch
    for (int i = tid; i < cnt; i += NMS_BDIM) {
        const float4* c4 = (const float4*)(blk + (size_t)i * 8);
        float4 lo = c4[0], hi = c4[1];
        s_conf[i] = lo.x; s_cx[i] = lo.y; s_cy[i] = lo.z; s_w[i] = lo.w;
        s_h[i]   = hi.x; s_cls[i] = hi.y; s_idx[i] = hi.z;
    }
    __syncthreads();

    // rank-sort (descending conf, ties -> lower concat idx)  == top_k semantics
    for (int i = tid; i < cnt; i += NMS_BDIM) {
        float ci = s_conf[i], ii = s_idx[i];
        int rank = 0;
        for (int j = 0; j < cnt; ++j) {
            float cj = s_conf[j];
            rank += (cj > ci) || (cj == ci && s_idx[j] < ii);
        }
        float cx = s_cx[i], cy = s_cy[i], w = s_w[i], h = s_h[i];
        r_conf[rank] = ci; r_cx[rank] = cx; r_cy[rank] = cy;
        r_w[rank] = w;     r_h[rank] = h;   r_cls[rank] = s_cls[i];
        s_x1[rank] = cx - 0.5f * w;
        s_y1[rank] = cy - 0.5f * h;
        s_x2[rank] = cx + 0.5f * w;
        s_y2[rank] = cy + 0.5f * h;
    }
    __syncthreads();

    // suppression bitmask (iou > 0.3 && same class)
    int nwords = (cnt + 63) >> 6;
    for (int t = tid; t < cnt * NW; t += NMS_BDIM) {
        int i  = t >> 2;
        int wi = t & 3;
        if (wi >= nwords) continue;
        float xi1 = s_x1[i], yi1 = s_y1[i], xi2 = s_x2[i], yi2 = s_y2[i];
        float cli = r_cls[i];
        float area_i = (xi2 - xi1) * (yi2 - yi1);
        unsigned long long m = 0;
        int jbase = wi << 6;
        for (int b = 0; b < 64; ++b) {
            int j = jbase + b;
            if (j >= cnt) break;
            if (j == i) continue;
            float xl = fmaxf(xi1, s_x1[j]);
            float yt = fmaxf(yi1, s_y1[j]);
            float xr = fminf(xi2, s_x2[j]);
            float yb = fminf(yi2, s_y2[j]);
            float inter  = fmaxf(xr - xl, 0.f) * fmaxf(yb - yt, 0.f);
            float area_j = (s_x2[j] - s_x1[j]) * (s_y2[j] - s_y1[j]);
            float iou    = inter / fmaxf(area_i + area_j - inter, 1e-9f);
            if (iou > 0.3f && cli == r_cls[j]) m |= (1ull << b);
        }
        sup[i][wi] = m;
    }
    __syncthreads();

    // greedy scan (sequential, thread 0; cnt ~ 66 iterations)
    if (tid == 0) {
        unsigned long long km[NW];
        for (int w = 0; w < NW; ++w) km[w] = 0ull;
        for (int i = 0; i < cnt; ++i) {
            unsigned long long sbits = 0;
            for (int w = 0; w < nwords; ++w) sbits |= sup[i][w] & km[w];
            if (sbits == 0) km[i >> 6] |= (1ull << (i & 63));
        }
        for (int w = 0; w < NW; ++w) keepmask[w] = km[w];
    }
    __syncthreads();

    // write (KDET,7) = full 2100 floats, overwriting the scratch region
    float nf = (float)n;
    for (int t = tid; t < KDET * 7; t += NMS_BDIM) {
        int r = t / 7, c = t - r * 7;
        float v = 0.f;
        if (r < cnt && ((keepmask[r >> 6] >> (r & 63)) & 1ull)) {
            switch (c) {
                case 0: v = r_conf[r]; break;
                case 1: v = r_cx[r];   break;
                case 2: v = r_cy[r];   break;
                case 3: v = r_w[r];    break;
                case 4: v = r_h[r];    break;
                case 5: v = r_cls[r];  break;
                case 6: v = nf;        break;
            }
        }
        blk[t] = v;
    }
}

extern "C" void kernel_launch(void* const* d_in, const int* in_sizes, int n_in,
                              void* d_out, int out_size, void* d_ws, size_t ws_size,
                              hipStream_t stream) {
    const float* out13 = (const float*)d_in[0];
    const float* out26 = (const float*)d_in[1];
    const float* out52 = (const float*)d_in[2];
    const float* a13   = (const float*)d_in[3];
    const float* a26   = (const float*)d_in[4];
    const float* a52   = (const float*)d_in[5];
    const float* thr   = (const float*)d_in[6];
    float* out = (float*)d_out;

    int N = in_sizes[0] / (255 * 13 * 13);   // 64

    // d_ws deliberately untouched: using it costs a ~106us re-poison fill/iter.
    yolo_zero_kernel<<<1, 64, 0, stream>>>(out, N);
    int total  = N * 10647;                  // N * 3 * (169 + 676 + 2704)
    int blocks = (total + SCAN_BDIM - 1) / SCAN_BDIM;
    yolo_scan_kernel<<<blocks, SCAN_BDIM, 0, stream>>>(
        out13, out26, out52, a13, a26, a52, thr, N, out);
    yolo_nms_kernel<<<N, NMS_BDIM, 0, stream>>>(out);
}

// Round 4
// 288.947 us; speedup vs baseline: 1.1625x; 1.1081x over previous
//
#include <hip/hip_runtime.h>

#define CAP  256    // max candidates per image (expected ~66, ~23 sigma margin)
#define KDET 300
#define NW   4      // ceil(CAP/64) suppression-mask words
#define BDIM 1024   // 16 waves/CU: latency hiding for scan + decode phases

// One block per image, ONE dispatch total (empirically the cheapest harness
// configuration: every extra graph node / workspace touch cost 5-106us in
// rounds 1-2). Phases:
//  1) conf scan (float4, coalesced), LDS-append passing cells
//  2) decode: 16-lane group per candidate; 80-class argmax = 5 loads/lane
//     + shfl_xor reduce (first-max tie-break), box params broadcast-loaded
//  3) rank-sort by (conf desc, idx asc)  == jax.lax.top_k tie semantics
//  4a) suppression bitmask (iou>0.3 && same class) into LDS
//  4b) greedy scan, wave-parallel: rows in registers, ~15cy/candidate
//  5) write (KDET,7) rows, zeros for suppressed/invalid
__global__ __launch_bounds__(BDIM) void yolo_fused_kernel(
        const float* __restrict__ o13, const float* __restrict__ o26,
        const float* __restrict__ o52,
        const float* __restrict__ a13, const float* __restrict__ a26,
        const float* __restrict__ a52,
        const float* __restrict__ thresh_p,
        float* __restrict__ out) {
    int n   = blockIdx.x;
    int tid = threadIdx.x;

    __shared__ int   l_cnt;
    __shared__ int   l_pack[CAP];            // s<<16 | a<<12 | pix
    __shared__ float l_conf[CAP];
    __shared__ float s_conf[CAP], s_cx[CAP], s_cy[CAP], s_w[CAP], s_h[CAP],
                     s_cls[CAP], s_idx[CAP];
    __shared__ float r_conf[CAP], r_cx[CAP], r_cy[CAP], r_w[CAP], r_h[CAP], r_cls[CAP];
    __shared__ float s_x1[CAP], s_y1[CAP], s_x2[CAP], s_y2[CAP];
    __shared__ unsigned long long sup[CAP][NW];
    __shared__ unsigned long long keepmask[NW];

    if (tid == 0) l_cnt = 0;
    __syncthreads();

    float thr = *thresh_p;

    // ---- phase 1: conf scan ----
    // s=0 (13x13, HW=169, odd -> scalar): 3 planes x 169 = 507 loads
    for (int t = tid; t < 507; t += BDIM) {
        int a = t / 169, pix = t - a * 169;
        float conf = o13[((size_t)(n * 255 + a * 85)) * 169 + pix];
        if (conf > thr) {
            int slot = atomicAdd(&l_cnt, 1);
            if (slot < CAP) { l_pack[slot] = (0 << 16) | (a << 12) | pix; l_conf[slot] = conf; }
        }
    }
    // s=1 (26x26, HW=676): 3 planes x 169 float4
    for (int t = tid; t < 507; t += BDIM) {
        int a = t / 169, v = t - a * 169;
        const float4 c4 = *(const float4*)(o26 + ((size_t)(n * 255 + a * 85)) * 676 + v * 4);
        #pragma unroll
        for (int k = 0; k < 4; ++k) {
            float conf = (&c4.x)[k];
            if (conf > thr) {
                int slot = atomicAdd(&l_cnt, 1);
                if (slot < CAP) { l_pack[slot] = (1 << 16) | (a << 12) | (v * 4 + k); l_conf[slot] = conf; }
            }
        }
    }
    // s=2 (52x52, HW=2704): 3 planes x 676 float4
    for (int t = tid; t < 2028; t += BDIM) {
        int a = t / 676, v = t - a * 676;
        const float4 c4 = *(const float4*)(o52 + ((size_t)(n * 255 + a * 85)) * 2704 + v * 4);
        #pragma unroll
        for (int k = 0; k < 4; ++k) {
            float conf = (&c4.x)[k];
            if (conf > thr) {
                int slot = atomicAdd(&l_cnt, 1);
                if (slot < CAP) { l_pack[slot] = (2 << 16) | (a << 12) | (v * 4 + k); l_conf[slot] = conf; }
            }
        }
    }
    __syncthreads();
    int cnt = l_cnt < CAP ? l_cnt : CAP;     // cnt <= 256 < KDET

    // ---- phase 2: decode, one 16-lane group per candidate ----
    // 80 classes = 5 per lane (c = lane, lane+16, ..., lane+64), strict '>'
    // keeps first occurrence within a lane; cross-lane reduce prefers equal
    // value at lower class -> exact jnp.argmax (first max) semantics.
    {
        int lane  = tid & 15;
        int group = tid >> 4;                // 64 groups
        for (int i = group; i < cnt; i += (BDIM >> 4)) {
            int pk  = l_pack[i];
            int s   = pk >> 16;
            int a   = (pk >> 12) & 0xF;
            int pix = pk & 0xFFF;
            const float* op = (s == 0) ? o13 : (s == 1) ? o26 : o52;
            const float* an = (s == 0) ? a13 : (s == 1) ? a26 : a52;
            int   HW     = (s == 0) ? 169 : (s == 1) ? 676 : 2704;
            int   W      = (s == 0) ? 13  : (s == 1) ? 26  : 52;
            float stride = (s == 0) ? 32.f : (s == 1) ? 16.f : 8.f;
            int   base   = (s == 0) ? 0   : (s == 1) ? 507 : 2535;

            const float* p = op + ((size_t)(n * 255 + a * 85)) * HW + pix;

            // partial argmax over own 5 classes
            float bestv = p[(size_t)(5 + lane) * HW];
            int   bestc = lane;
            #pragma unroll
            for (int k = 1; k < 5; ++k) {
                int c = lane + 16 * k;
                float v = p[(size_t)(5 + c) * HW];
                if (v > bestv) { bestv = v; bestc = c; }
            }
            // 16-lane reduce (explicit width=16: xor stays in the group)
            #pragma unroll
            for (int m = 8; m; m >>= 1) {
                float ov = __shfl_xor(bestv, m, 16);
                int   oc = __shfl_xor(bestc, m, 16);
                if (ov > bestv || (ov == bestv && oc < bestc)) { bestv = ov; bestc = oc; }
            }

            if (lane == 0) {
                float o1 = p[(size_t)1 * HW];
                float o2 = p[(size_t)2 * HW];
                float o3 = p[(size_t)3 * HW];
                float o4 = p[(size_t)4 * HW];
                int gx = pix % W, gy = pix / W;
                s_conf[i] = l_conf[i];
                s_cx[i] = ((float)gx + o1) * stride;
                s_cy[i] = ((float)gy + o2) * stride;
                s_w[i]  = expf(o3) * an[2 * a + 0];
                s_h[i]  = expf(o4) * an[2 * a + 1];
                s_cls[i] = (float)bestc;
                s_idx[i] = (float)(base + pix * 3 + a);
            }
        }
    }
    __syncthreads();

    // ---- phase 3: rank-sort (descending conf, ties -> lower concat idx) ----
    for (int i = tid; i < cnt; i += BDIM) {
        float ci = s_conf[i], ii = s_idx[i];
        int rank = 0;
        for (int j = 0; j < cnt; ++j) {
            float cj = s_conf[j];
            rank += (cj > ci) || (cj == ci && s_idx[j] < ii);
        }
        float cx = s_cx[i], cy = s_cy[i], w = s_w[i], h = s_h[i];
        r_conf[rank] = ci; r_cx[rank] = cx; r_cy[rank] = cy;
        r_w[rank] = w;     r_h[rank] = h;   r_cls[rank] = s_cls[i];
        s_x1[rank] = cx - 0.5f * w;
        s_y1[rank] = cy - 0.5f * h;
        s_x2[rank] = cx + 0.5f * w;
        s_y2[rank] = cy + 0.5f * h;
    }
    __syncthreads();

    // ---- phase 4a: suppression bitmask ----
    int nwords = (cnt + 63) >> 6;
    for (int t = tid; t < cnt * NW; t += BDIM) {
        int i  = t >> 2;
        int wi = t & 3;
        if (wi >= nwords) continue;
        float xi1 = s_x1[i], yi1 = s_y1[i], xi2 = s_x2[i], yi2 = s_y2[i];
        float cli = r_cls[i];
        float area_i = (xi2 - xi1) * (yi2 - yi1);
        unsigned long long m = 0;
        int jbase = wi << 6;
        for (int b = 0; b < 64; ++b) {
            int j = jbase + b;
            if (j >= cnt) break;
            if (j == i) continue;
            float xl = fmaxf(xi1, s_x1[j]);
            float yt = fmaxf(yi1, s_y1[j]);
            float xr = fminf(xi2, s_x2[j]);
            float yb = fminf(yi2, s_y2[j]);
            float inter  = fmaxf(xr - xl, 0.f) * fmaxf(yb - yt, 0.f);
            float area_j = (s_x2[j] - s_x1[j]) * (s_y2[j] - s_y1[j]);
            float iou    = inter / fmaxf(area_i + area_j - inter, 1e-9f);
            if (iou > 0.3f && cli == r_cls[j]) m |= (1ull << b);
        }
        sup[i][wi] = m;
    }
    __syncthreads();

    // ---- phase 4b: greedy scan, wave-parallel (wave 0) ----
    // Lane L owns rows j = L, L+64, L+128, L+192 ("suppressed-by" masks,
    // pre-loaded to registers). km replicated in every lane; per candidate i:
    // owner lane tests row&km, keep-bit broadcast via shfl. Register-only loop.
    if (tid < 64) {
        unsigned long long rA[NW] = {0,0,0,0}, rB[NW] = {0,0,0,0},
                           rC[NW] = {0,0,0,0}, rD[NW] = {0,0,0,0};
        #pragma unroll
        for (int w = 0; w < NW; ++w) {
            if (w < nwords) {
                if (tid       < cnt) rA[w] = sup[tid      ][w];
                if (tid + 64  < cnt) rB[w] = sup[tid + 64 ][w];
                if (tid + 128 < cnt) rC[w] = sup[tid + 128][w];
                if (tid + 192 < cnt) rD[w] = sup[tid + 192][w];
            }
        }
        unsigned long long km[NW] = {0,0,0,0};
        for (int i = 0; i < cnt; ++i) {
            int r = i >> 6;
            unsigned long long sb;
            switch (r) {
                case 0:  sb = (rA[0]&km[0])|(rA[1]&km[1])|(rA[2]&km[2])|(rA[3]&km[3]); break;
                case 1:  sb = (rB[0]&km[0])|(rB[1]&km[1])|(rB[2]&km[2])|(rB[3]&km[3]); break;
                case 2:  sb = (rC[0]&km[0])|(rC[1]&km[1])|(rC[2]&km[2])|(rC[3]&km[3]); break;
                default: sb = (rD[0]&km[0])|(rD[1]&km[1])|(rD[2]&km[2])|(rD[3]&km[3]); break;
            }
            int keep_i = (sb == 0ull) ? 1 : 0;
            keep_i = __shfl(keep_i, i & 63);     // broadcast owner's verdict
            if (keep_i) km[r] |= (1ull << (i & 63));
        }
        if (tid == 0) {
            #pragma unroll
            for (int w = 0; w < NW; ++w) keepmask[w] = km[w];
        }
    }
    __syncthreads();

    // ---- phase 5: write (KDET,7) ----
    float* obase = out + (size_t)n * KDET * 7;
    float nf = (float)n;
    for (int t = tid; t < KDET * 7; t += BDIM) {
        int r = t / 7, c = t - r * 7;
        float v = 0.f;
        if (r < cnt && ((keepmask[r >> 6] >> (r & 63)) & 1ull)) {
            switch (c) {
                case 0: v = r_conf[r]; break;
                case 1: v = r_cx[r];   break;
                case 2: v = r_cy[r];   break;
                case 3: v = r_w[r];    break;
                case 4: v = r_h[r];    break;
                case 5: v = r_cls[r];  break;
                case 6: v = nf;        break;
            }
        }
        obase[t] = v;
    }
}

extern "C" void kernel_launch(void* const* d_in, const int* in_sizes, int n_in,
                              void* d_out, int out_size, void* d_ws, size_t ws_size,
                              hipStream_t stream) {
    const float* out13 = (const float*)d_in[0];
    const float* out26 = (const float*)d_in[1];
    const float* out52 = (const float*)d_in[2];
    const float* a13   = (const float*)d_in[3];
    const float* a26   = (const float*)d_in[4];
    const float* a52   = (const float*)d_in[5];
    const float* thr   = (const float*)d_in[6];
    float* out = (float*)d_out;

    int N = in_sizes[0] / (255 * 13 * 13);   // 64

    // Single dispatch, no workspace: every extra graph node / ws touch cost
    // 5-106us in rounds 1-2. All parallelism is intra-block (16 waves/CU).
    yolo_fused_kernel<<<N, BDIM, 0, stream>>>(out13, out26, out52,
                                              a13, a26, a52, thr, out);
}